// Round 9
// baseline (229.953 us; speedup 1.0000x reference)
//
#include <hip/hip_runtime.h>
#include <hip/hip_bf16.h>

#define BB 4
#define SS 2048
#define EE 512
#define HH 8
#define DD 64

typedef __attribute__((ext_vector_type(8))) short bf16x8;   // 8 bf16 = 4 VGPRs
typedef __attribute__((ext_vector_type(4))) float f32x4;

__device__ __forceinline__ unsigned short f2bf(float f) {
    __hip_bfloat16 h = __float2bfloat16(f);   // round-to-nearest
    return *reinterpret_cast<unsigned short*>(&h);
}
__device__ __forceinline__ unsigned int pk2(float lo, float hi) {
    return ((unsigned int)f2bf(hi) << 16) | (unsigned int)f2bf(lo);
}

// Async global->LDS DMA, 16 B per lane. LDS dst = wave-uniform base + lane*16
// (m104/m108). Drained by the vmcnt(0) inside __syncthreads().
__device__ __forceinline__ void gll16(const unsigned short* g, unsigned short* l) {
    __builtin_amdgcn_global_load_lds(
        (const __attribute__((address_space(1))) unsigned int*)g,
        (__attribute__((address_space(3))) unsigned int*)l,
        16, 0, 0);
}

// ---------------------------------------------------------------------------
// fp32 -> bf16 cast, 5 tensors in one launch (blockIdx.y selects).
// ---------------------------------------------------------------------------
__global__ __launch_bounds__(256)
void cast_all(const float* __restrict__ x,
              const float* __restrict__ wq, const float* __restrict__ wk,
              const float* __restrict__ wv, const float* __restrict__ wo,
              unsigned short* __restrict__ xb,
              unsigned short* __restrict__ wqb, unsigned short* __restrict__ wkb,
              unsigned short* __restrict__ wvb, unsigned short* __restrict__ wob)
{
    const int t = blockIdx.y;
    const float* src; unsigned short* dst; int n4;
    switch (t) {
        case 0: src = x;  dst = xb;  n4 = (BB*SS*EE)/4; break;
        case 1: src = wq; dst = wqb; n4 = (EE*EE)/4; break;
        case 2: src = wk; dst = wkb; n4 = (EE*EE)/4; break;
        case 3: src = wv; dst = wvb; n4 = (EE*EE)/4; break;
        default: src = wo; dst = wob; n4 = (EE*EE)/4; break;
    }
    const int i = blockIdx.x * 256 + threadIdx.x;
    if (i >= n4) return;
    const float4 v = reinterpret_cast<const float4*>(src)[i];
    ushort4 o;
    o.x = f2bf(v.x); o.y = f2bf(v.y); o.z = f2bf(v.z); o.w = f2bf(v.w);
    reinterpret_cast<ushort4*>(dst)[i] = o;
}

// ---------------------------------------------------------------------------
// MFMA GEMM, ping-pong DMA pipeline: C = A(bf16) @ W(bf16)^T + bias.
// TM x 128 tile, 4 waves, 16x16x32 bf16 MFMA, BK=32.
// Per iter: (1) issue next tile's global_load_lds into buffer B (async, no
// VGPR round-trip), (2) MFMA on buffer A, (3) ONE __syncthreads — its
// vmcnt(0) drain finds the DMAs already landed (compute covered the
// latency). r3/r4's REGISTER prefetch failed because staging stores forced
// per-iter vmcnt(0) waits; DMA prefetch has no such dependency.
// LDS rows unpadded (32 shorts); XOR chunk swizzle keeps b128 frag reads
// 2-way max (free, m136). TRANSPOSE_V: z==2 writes Vt[b][h][d][s].
// ---------------------------------------------------------------------------
template<typename OutT, bool TRANSPOSE_V, int TM>
__global__ __launch_bounds__(256)
void gemm_mfma_nt(const unsigned short* __restrict__ A,
                  const unsigned short* __restrict__ W0, const float* __restrict__ b0, OutT* __restrict__ C0,
                  const unsigned short* __restrict__ W1, const float* __restrict__ b1, OutT* __restrict__ C1,
                  const unsigned short* __restrict__ W2, const float* __restrict__ b2, OutT* __restrict__ C2,
                  int M, int N, int K)
{
    const unsigned short* W = (blockIdx.z == 0) ? W0 : (blockIdx.z == 1) ? W1 : W2;
    const float* bias       = (blockIdx.z == 0) ? b0 : (blockIdx.z == 1) ? b1 : b2;
    OutT* C                 = (blockIdx.z == 0) ? C0 : (blockIdx.z == 1) ? C1 : C2;

    constexpr int MT = TM / 32;               // m-tiles of 16 per wave (4 or 2)
    __shared__ unsigned short As[2][TM * 32]; // [row][32] chunk-swizzled
    __shared__ unsigned short Bs[2][128 * 32];

    const int tid  = threadIdx.x;
    const int wave = tid >> 6, lane = tid & 63;
    const int quad = lane >> 4, r16 = lane & 15;
    const int m0 = blockIdx.x * TM, n0 = blockIdx.y * 128;
    const int wm0 = (wave >> 1) * (TM / 2), wn0 = (wave & 1) * 64;

    f32x4 acc[MT][4];
    const f32x4 zero = {0.f, 0.f, 0.f, 0.f};
    #pragma unroll
    for (int i = 0; i < MT; ++i)
        #pragma unroll
        for (int j = 0; j < 4; ++j) acc[i][j] = zero;

    const int swz = (r16 >> 1) & 3;   // fragment-read chunk swizzle

    // Staging lambdas (wave-uniform LDS base + lane*16).
    auto stage = [&](int buf, int k0) {
        #pragma unroll
        for (int j = 0; j < TM / 64; ++j) {
            const int cb = wave * 64 + j * 256;
            const int c  = cb + lane;
            const int row = c >> 2, cc = (c & 3) ^ ((row >> 1) & 3);
            gll16(&A[(size_t)(m0 + row) * K + k0 + cc * 8], &As[buf][cb * 8]);
        }
        #pragma unroll
        for (int j = 0; j < 2; ++j) {
            const int cb = wave * 64 + j * 256;
            const int c  = cb + lane;
            const int row = c >> 2, cc = (c & 3) ^ ((row >> 1) & 3);
            gll16(&W[(size_t)(n0 + row) * K + k0 + cc * 8], &Bs[buf][cb * 8]);
        }
    };

    stage(0, 0);
    __syncthreads();
    int cur = 0;

    for (int k0 = 0; k0 < K; k0 += 32) {
        if (k0 + 32 < K) stage(cur ^ 1, k0 + 32);   // async, lands during MFMA
        bf16x8 af[MT], bfr[4];
        #pragma unroll
        for (int t = 0; t < MT; ++t)
            af[t]  = *reinterpret_cast<bf16x8*>(&As[cur][((wm0 + t * 16 + r16) * 4 + (quad ^ swz)) * 8]);
        #pragma unroll
        for (int t = 0; t < 4; ++t)
            bfr[t] = *reinterpret_cast<bf16x8*>(&Bs[cur][((wn0 + t * 16 + r16) * 4 + (quad ^ swz)) * 8]);
        #pragma unroll
        for (int mt = 0; mt < MT; ++mt)
            #pragma unroll
            for (int nt = 0; nt < 4; ++nt)
                acc[mt][nt] = __builtin_amdgcn_mfma_f32_16x16x32_bf16(
                    af[mt], bfr[nt], acc[mt][nt], 0, 0, 0);
        __syncthreads();   // drains this iter's DMA (landed) + frag reads
        cur ^= 1;
    }

    // Epilogue. C/D layout: col = lane&15, row = quad*4 + reg (m89-verified).
    if (TRANSPOSE_V && blockIdx.z == 2) {
        #pragma unroll
        for (int mt = 0; mt < MT; ++mt) {
            const int m = m0 + wm0 + mt * 16 + quad * 4;   // 4 consecutive rows
            const int bb = m >> 11, s0 = m & (SS - 1);
            #pragma unroll
            for (int nt = 0; nt < 4; ++nt) {
                const int col = n0 + wn0 + nt * 16 + r16;
                const float bv = bias[col];
                ushort4 o;
                o.x = f2bf(acc[mt][nt][0] + bv);
                o.y = f2bf(acc[mt][nt][1] + bv);
                o.z = f2bf(acc[mt][nt][2] + bv);
                o.w = f2bf(acc[mt][nt][3] + bv);
                *reinterpret_cast<ushort4*>(
                    &((unsigned short*)C2)[(size_t)bb * EE * SS + (size_t)col * SS + s0]) = o;
            }
        }
        return;
    }
    #pragma unroll
    for (int mt = 0; mt < MT; ++mt) {
        #pragma unroll
        for (int nt = 0; nt < 4; ++nt) {
            const int col = n0 + wn0 + nt * 16 + r16;
            const float bv = bias[col];
            #pragma unroll
            for (int r = 0; r < 4; ++r) {
                const int row = m0 + wm0 + mt * 16 + quad * 4 + r;
                const float v = acc[mt][nt][r] + bv;
                if constexpr (sizeof(OutT) == 2)
                    C[(size_t)row * N + col] = (OutT)f2bf(v);
                else
                    C[(size_t)row * N + col] = (OutT)v;
            }
        }
    }
}

// ---------------------------------------------------------------------------
// MFMA flash attention, round 9 = r8 compute core + ping-pong DMA pipeline.
//  - S^T = mfma(kf, qf); per-lane softmax scale; per-lane l; packed b64 P
//    writes into per-wave Ps (APAD=68).
//  - K/V double-buffered; next tile's global_load_lds issued BEFORE compute,
//    ONE __syncthreads per iter (drain finds DMA landed).
//  - XOR chunk swizzle on unpadded 64-short rows: frag reads 2-way max.
// ---------------------------------------------------------------------------
#define APAD 68

__global__ __launch_bounds__(256)
void attn_mfma(const unsigned short* __restrict__ Q,
               const unsigned short* __restrict__ K,
               const unsigned short* __restrict__ Vt,
               const float* __restrict__ ent,
               unsigned short* __restrict__ O)
{
    __shared__ unsigned short Ks[2][64 * 64];    // [k][64] chunk-swizzled
    __shared__ unsigned short Vs[2][64 * 64];    // [d][64] chunk-swizzled
    __shared__ unsigned short Ps[4][16 * APAD];  // per-wave [q16][k64]

    const int tid  = threadIdx.x;
    const int wave = tid >> 6, lane = tid & 63;
    const int quad = lane >> 4, r16 = lane & 15;
    const int q0 = blockIdx.x * 64;
    const int h  = blockIdx.y, b = blockIdx.z;
    const size_t base    = (size_t)b * SS * EE + (size_t)h * DD;   // Q/K/O rows
    const size_t base_vt = ((size_t)b * HH + h) * DD * SS;         // Vt rows

    // Q fragments once, direct from global. B-operand: n = q = r16.
    const int qrow = q0 + wave * 16 + r16;
    bf16x8 qf0 = *reinterpret_cast<const bf16x8*>(&Q[base + (size_t)qrow * EE + quad * 8]);
    bf16x8 qf1 = *reinterpret_cast<const bf16x8*>(&Q[base + (size_t)qrow * EE + 32 + quad * 8]);

    // Per-lane row scale: entangle[q=r16 row] * 1/8 * log2(e).
    const float eqs = ent[q0 + wave * 16 + r16] * (0.125f * 1.44269504f);

    float l_lane = 0.f;
    f32x4 o_acc[4];
    const f32x4 zero = {0.f, 0.f, 0.f, 0.f};
    #pragma unroll
    for (int dt = 0; dt < 4; ++dt) o_acc[dt] = zero;

    unsigned short* pw = &Ps[wave][0];
    const int swz = r16 & 7;   // fragment-read chunk swizzle (8 chunks/row)

    auto stage = [&](int buf, int kb) {
        #pragma unroll
        for (int j = 0; j < 2; ++j) {
            const int cb = wave * 64 + j * 256;
            const int c  = cb + lane;
            const int row = c >> 3, cc = (c & 7) ^ (row & 7);
            gll16(&K[base + (size_t)(kb + row) * EE + cc * 8], &Ks[buf][cb * 8]);
            gll16(&Vt[base_vt + (size_t)row * SS + kb + cc * 8], &Vs[buf][cb * 8]);
        }
    };

    stage(0, 0);
    __syncthreads();
    int cur = 0;

    for (int kt = 0; kt < SS / 64; ++kt) {
        if (kt + 1 < SS / 64) stage(cur ^ 1, (kt + 1) * 64);   // async prefetch

        // S^T = mfma(kf, qf): lane(quad,r16) gets st[tn][r] =
        //   S[q = r16][k = tn*16 + quad*4 + r].
        f32x4 st[4];
        #pragma unroll
        for (int tn = 0; tn < 4; ++tn) st[tn] = zero;
        #pragma unroll
        for (int tn = 0; tn < 4; ++tn) {
            bf16x8 kf0 = *reinterpret_cast<const bf16x8*>(&Ks[cur][((tn * 16 + r16) * 8 + (quad ^ swz)) * 8]);
            bf16x8 kf1 = *reinterpret_cast<const bf16x8*>(&Ks[cur][((tn * 16 + r16) * 8 + ((quad + 4) ^ swz)) * 8]);
            st[tn] = __builtin_amdgcn_mfma_f32_16x16x32_bf16(kf0, qf0, st[tn], 0, 0, 0);
            st[tn] = __builtin_amdgcn_mfma_f32_16x16x32_bf16(kf1, qf1, st[tn], 0, 0, 0);
        }

        // V fragments (independent of softmax -> overlaps it).
        bf16x8 vf0[4], vf1[4];
        #pragma unroll
        for (int dt = 0; dt < 4; ++dt) {
            vf0[dt] = *reinterpret_cast<const bf16x8*>(&Vs[cur][((dt * 16 + r16) * 8 + (quad ^ swz)) * 8]);
            vf1[dt] = *reinterpret_cast<const bf16x8*>(&Vs[cur][((dt * 16 + r16) * 8 + ((quad + 4) ^ swz)) * 8]);
        }

        // m=0 softmax; pack 4 consecutive-k p's -> one b64 LDS write per tn.
        #pragma unroll
        for (int tn = 0; tn < 4; ++tn) {
            const float p0 = exp2f(st[tn][0] * eqs);
            const float p1 = exp2f(st[tn][1] * eqs);
            const float p2 = exp2f(st[tn][2] * eqs);
            const float p3 = exp2f(st[tn][3] * eqs);
            l_lane += (p0 + p1) + (p2 + p3);
            uint2 d;
            d.x = pk2(p0, p1);
            d.y = pk2(p2, p3);
            *reinterpret_cast<uint2*>(&pw[r16 * APAD + tn * 16 + quad * 4]) = d;
        }
        // Per-wave P buffer: in-wave lgkm ordering suffices, no barrier.

        // PV: a = P[m=q=r16][k = quad*8+j], b = Vs[n=d=r16][k].
        bf16x8 pf0 = *reinterpret_cast<bf16x8*>(&pw[r16 * APAD + quad * 8]);
        bf16x8 pf1 = *reinterpret_cast<bf16x8*>(&pw[r16 * APAD + 32 + quad * 8]);
        #pragma unroll
        for (int dt = 0; dt < 4; ++dt) {
            o_acc[dt] = __builtin_amdgcn_mfma_f32_16x16x32_bf16(pf0, vf0[dt], o_acc[dt], 0, 0, 0);
            o_acc[dt] = __builtin_amdgcn_mfma_f32_16x16x32_bf16(pf1, vf1[dt], o_acc[dt], 0, 0, 0);
        }

        __syncthreads();   // drains this iter's DMA (landed during compute)
        cur ^= 1;
    }

    // l: per-lane total for q = r16; sum the 4 quads.
    float l = l_lane;
    l += __shfl_xor(l, 16, 64);
    l += __shfl_xor(l, 32, 64);

    // Epilogue: O rows q = quad*4+r; l for that q lives in lane (quad*4+r).
    #pragma unroll
    for (int r = 0; r < 4; ++r) {
        const float il = 1.0f / __shfl(l, quad * 4 + r, 64);
        const int q = q0 + wave * 16 + quad * 4 + r;
        #pragma unroll
        for (int dt = 0; dt < 4; ++dt)
            O[base + (size_t)q * EE + dt * 16 + r16] = f2bf(o_acc[dt][r] * il);
    }
}

extern "C" void kernel_launch(void* const* d_in, const int* in_sizes, int n_in,
                              void* d_out, int out_size, void* d_ws, size_t ws_size,
                              hipStream_t stream) {
    const float* x   = (const float*)d_in[0];
    const float* ent = (const float*)d_in[1];
    const float* Wq  = (const float*)d_in[2];
    const float* bq  = (const float*)d_in[3];
    const float* Wk  = (const float*)d_in[4];
    const float* bk  = (const float*)d_in[5];
    const float* Wv  = (const float*)d_in[6];
    const float* bv  = (const float*)d_in[7];
    const float* Wo  = (const float*)d_in[8];
    const float* bo  = (const float*)d_in[9];
    float* out = (float*)d_out;

    const size_t n_x = (size_t)BB * SS * EE;   // 4 Mi elements
    const size_t n_w = (size_t)EE * EE;

    unsigned short* xb  = (unsigned short*)d_ws;
    unsigned short* wqb = xb + n_x;
    unsigned short* wkb = wqb + n_w;
    unsigned short* wvb = wkb + n_w;
    unsigned short* wob = wvb + n_w;
    unsigned short* Qb  = wob + n_w;
    unsigned short* Kb  = Qb + n_x;
    unsigned short* Vtb = Kb + n_x;   // [b][h][d][s]
    unsigned short* AOb = Vtb + n_x;

    const int M = BB * SS;  // 8192

    dim3 gc(4096, 5, 1);
    cast_all<<<gc, 256, 0, stream>>>(x, Wq, Wk, Wv, Wo, xb, wqb, wkb, wvb, wob);

    // Fused QKV projection.
    dim3 gq(M / 128, EE / 128, 3);
    gemm_mfma_nt<unsigned short, true, 128><<<gq, 256, 0, stream>>>(
        xb, wqb, bq, Qb, wkb, bk, Kb, wvb, bv, Vtb, M, EE, EE);

    dim3 ga(SS / 64, HH, BB);
    attn_mfma<<<ga, 256, 0, stream>>>(Qb, Kb, Vtb, ent, AOb);

    // Out-proj: 64x128 tiles -> 512 blocks (2/CU).
    dim3 go(M / 64, EE / 128, 1);
    gemm_mfma_nt<float, false, 64><<<go, 256, 0, stream>>>(
        AOb, wob, bo, out, wob, bo, out, wob, bo, out, M, EE, EE);
}

// Round 10
// 211.703 us; speedup vs baseline: 1.0862x; 1.0862x over previous
//
#include <hip/hip_runtime.h>
#include <hip/hip_bf16.h>

#define BB 4
#define SS 2048
#define EE 512
#define HH 8
#define DD 64

typedef __attribute__((ext_vector_type(8))) short bf16x8;   // 8 bf16 = 4 VGPRs
typedef __attribute__((ext_vector_type(4))) float f32x4;

// Fast fp32->bf16 round-to-nearest-even (exact for finite values; no NaN in
// this problem's data paths).
__device__ __forceinline__ unsigned short f2bf(float f) {
    unsigned int u = __float_as_uint(f);
    u += 0x7FFFu + ((u >> 16) & 1u);
    return (unsigned short)(u >> 16);
}
__device__ __forceinline__ unsigned int pk2(float lo, float hi) {
    return ((unsigned int)f2bf(hi) << 16) | (unsigned int)f2bf(lo);
}

// Async global->LDS DMA, 16 B per lane. LDS dst = wave-uniform base + lane*16
// (m104/m108). Drained by the vmcnt(0) inside __syncthreads().
__device__ __forceinline__ void gll16(const unsigned short* g, unsigned short* l) {
    __builtin_amdgcn_global_load_lds(
        (const __attribute__((address_space(1))) unsigned int*)g,
        (__attribute__((address_space(3))) unsigned int*)l,
        16, 0, 0);
}

// ---------------------------------------------------------------------------
// fp32 -> bf16 cast, 5 tensors in one launch (blockIdx.y selects).
// ---------------------------------------------------------------------------
__global__ __launch_bounds__(256)
void cast_all(const float* __restrict__ x,
              const float* __restrict__ wq, const float* __restrict__ wk,
              const float* __restrict__ wv, const float* __restrict__ wo,
              unsigned short* __restrict__ xb,
              unsigned short* __restrict__ wqb, unsigned short* __restrict__ wkb,
              unsigned short* __restrict__ wvb, unsigned short* __restrict__ wob)
{
    const int t = blockIdx.y;
    const float* src; unsigned short* dst; int n4;
    switch (t) {
        case 0: src = x;  dst = xb;  n4 = (BB*SS*EE)/4; break;
        case 1: src = wq; dst = wqb; n4 = (EE*EE)/4; break;
        case 2: src = wk; dst = wkb; n4 = (EE*EE)/4; break;
        case 3: src = wv; dst = wvb; n4 = (EE*EE)/4; break;
        default: src = wo; dst = wob; n4 = (EE*EE)/4; break;
    }
    const int i = blockIdx.x * 256 + threadIdx.x;
    if (i >= n4) return;
    const float4 v = reinterpret_cast<const float4*>(src)[i];
    ushort4 o;
    o.x = f2bf(v.x); o.y = f2bf(v.y); o.z = f2bf(v.z); o.w = f2bf(v.w);
    reinterpret_cast<ushort4*>(dst)[i] = o;
}

// ---------------------------------------------------------------------------
// MFMA GEMM (r8-proven): C = A(bf16) @ W(bf16)^T + bias.
// TM x 128 tile, 4 waves, 16x16x32 bf16 MFMA, BK=32, simple 2-barrier loop,
// global_load_lds width-16 staging, XOR chunk swizzle (2-way max, free).
// TRANSPOSE_V: blockIdx.z==2 writes C transposed per-head as Vt[b][h][d][s].
// ---------------------------------------------------------------------------
template<typename OutT, bool TRANSPOSE_V, int TM>
__global__ __launch_bounds__(256)
void gemm_mfma_nt(const unsigned short* __restrict__ A,
                  const unsigned short* __restrict__ W0, const float* __restrict__ b0, OutT* __restrict__ C0,
                  const unsigned short* __restrict__ W1, const float* __restrict__ b1, OutT* __restrict__ C1,
                  const unsigned short* __restrict__ W2, const float* __restrict__ b2, OutT* __restrict__ C2,
                  int M, int N, int K)
{
    const unsigned short* W = (blockIdx.z == 0) ? W0 : (blockIdx.z == 1) ? W1 : W2;
    const float* bias       = (blockIdx.z == 0) ? b0 : (blockIdx.z == 1) ? b1 : b2;
    OutT* C                 = (blockIdx.z == 0) ? C0 : (blockIdx.z == 1) ? C1 : C2;

    constexpr int MT = TM / 32;             // m-tiles of 16 per wave (4 or 2)
    __shared__ unsigned short As[TM * 32];  // [row][32] chunk-swizzled
    __shared__ unsigned short Bs[128 * 32];

    const int tid  = threadIdx.x;
    const int wave = tid >> 6, lane = tid & 63;
    const int quad = lane >> 4, r16 = lane & 15;
    const int m0 = blockIdx.x * TM, n0 = blockIdx.y * 128;
    const int wm0 = (wave >> 1) * (TM / 2), wn0 = (wave & 1) * 64;

    f32x4 acc[MT][4];
    const f32x4 zero = {0.f, 0.f, 0.f, 0.f};
    #pragma unroll
    for (int i = 0; i < MT; ++i)
        #pragma unroll
        for (int j = 0; j < 4; ++j) acc[i][j] = zero;

    const int swz = (r16 >> 1) & 3;   // fragment-read chunk swizzle

    for (int k0 = 0; k0 < K; k0 += 32) {
        __syncthreads();   // previous iteration's frag reads done
        #pragma unroll
        for (int j = 0; j < TM / 64; ++j) {
            const int cb = wave * 64 + j * 256;       // wave-uniform chunk base
            const int c  = cb + lane;                 // this lane's chunk
            const int row = c >> 2, cc = (c & 3) ^ ((row >> 1) & 3);
            gll16(&A[(size_t)(m0 + row) * K + k0 + cc * 8], &As[cb * 8]);
        }
        #pragma unroll
        for (int j = 0; j < 2; ++j) {
            const int cb = wave * 64 + j * 256;
            const int c  = cb + lane;
            const int row = c >> 2, cc = (c & 3) ^ ((row >> 1) & 3);
            gll16(&W[(size_t)(n0 + row) * K + k0 + cc * 8], &Bs[cb * 8]);
        }
        __syncthreads();   // vmcnt(0) drain completes the DMA
        bf16x8 af[MT], bfr[4];
        #pragma unroll
        for (int t = 0; t < MT; ++t)
            af[t]  = *reinterpret_cast<bf16x8*>(&As[((wm0 + t * 16 + r16) * 4 + (quad ^ swz)) * 8]);
        #pragma unroll
        for (int t = 0; t < 4; ++t)
            bfr[t] = *reinterpret_cast<bf16x8*>(&Bs[((wn0 + t * 16 + r16) * 4 + (quad ^ swz)) * 8]);
        #pragma unroll
        for (int mt = 0; mt < MT; ++mt)
            #pragma unroll
            for (int nt = 0; nt < 4; ++nt)
                acc[mt][nt] = __builtin_amdgcn_mfma_f32_16x16x32_bf16(
                    af[mt], bfr[nt], acc[mt][nt], 0, 0, 0);
    }

    // Epilogue. C/D layout: col = lane&15, row = quad*4 + reg (m89-verified).
    if (TRANSPOSE_V && blockIdx.z == 2) {
        #pragma unroll
        for (int mt = 0; mt < MT; ++mt) {
            const int m = m0 + wm0 + mt * 16 + quad * 4;   // 4 consecutive rows
            const int bb = m >> 11, s0 = m & (SS - 1);
            #pragma unroll
            for (int nt = 0; nt < 4; ++nt) {
                const int col = n0 + wn0 + nt * 16 + r16;
                const float bv = bias[col];
                ushort4 o;
                o.x = f2bf(acc[mt][nt][0] + bv);
                o.y = f2bf(acc[mt][nt][1] + bv);
                o.z = f2bf(acc[mt][nt][2] + bv);
                o.w = f2bf(acc[mt][nt][3] + bv);
                *reinterpret_cast<ushort4*>(
                    &((unsigned short*)C2)[(size_t)bb * EE * SS + (size_t)col * SS + s0]) = o;
            }
        }
        return;
    }
    #pragma unroll
    for (int mt = 0; mt < MT; ++mt) {
        #pragma unroll
        for (int nt = 0; nt < 4; ++nt) {
            const int col = n0 + wn0 + nt * 16 + r16;
            const float bv = bias[col];
            #pragma unroll
            for (int r = 0; r < 4; ++r) {
                const int row = m0 + wm0 + mt * 16 + quad * 4 + r;
                const float v = acc[mt][nt][r] + bv;
                if constexpr (sizeof(OutT) == 2)
                    C[(size_t)row * N + col] = (OutT)f2bf(v);
                else
                    C[(size_t)row * N + col] = (OutT)v;
            }
        }
    }
}

// ---------------------------------------------------------------------------
// MFMA flash attention, round 10 = r8 structure with Tk=128 per iteration.
// Halves barrier count (16 iters), doubles MFMA per drain; single-buffer
// 2-barrier shape retained (r9's double-buffer traded occupancy and lost).
//  - S^T = mfma(kf, qf); per-lane scale; per-lane l; packed b64 P writes.
//  - K [128 k][64 d], V [64 d][128 k], both DMA-staged, XOR chunk-swizzled
//    (all read/write patterns verified 2-way max bank aliasing = free).
// ---------------------------------------------------------------------------
#define PROW 136   // Ps row stride in shorts (17 dword-windows -> conflict-free)

__global__ __launch_bounds__(256)
void attn_mfma(const unsigned short* __restrict__ Q,
               const unsigned short* __restrict__ K,
               const unsigned short* __restrict__ Vt,
               const float* __restrict__ ent,
               unsigned short* __restrict__ O)
{
    __shared__ unsigned short Ks[128 * 64];      // [k][64] chunk-swizzled
    __shared__ unsigned short Vs[64 * 128];      // [d][128] chunk-swizzled
    __shared__ unsigned short Ps[4][16 * PROW];  // per-wave [q16][k128]

    const int tid  = threadIdx.x;
    const int wave = tid >> 6, lane = tid & 63;
    const int quad = lane >> 4, r16 = lane & 15;
    const int q0 = blockIdx.x * 64;
    const int h  = blockIdx.y, b = blockIdx.z;
    const size_t base    = (size_t)b * SS * EE + (size_t)h * DD;   // Q/K/O rows
    const size_t base_vt = ((size_t)b * HH + h) * DD * SS;         // Vt rows

    // Q fragments once, direct from global. B-operand: n = q = r16.
    const int qrow = q0 + wave * 16 + r16;
    bf16x8 qf0 = *reinterpret_cast<const bf16x8*>(&Q[base + (size_t)qrow * EE + quad * 8]);
    bf16x8 qf1 = *reinterpret_cast<const bf16x8*>(&Q[base + (size_t)qrow * EE + 32 + quad * 8]);

    // Per-lane row scale: entangle[q=r16 row] * 1/8 * log2(e).
    const float eqs = ent[q0 + wave * 16 + r16] * (0.125f * 1.44269504f);

    float l_lane = 0.f;
    f32x4 o_acc[4];
    const f32x4 zero = {0.f, 0.f, 0.f, 0.f};
    #pragma unroll
    for (int dt = 0; dt < 4; ++dt) o_acc[dt] = zero;

    unsigned short* pw = &Ps[wave][0];
    const int swzk = r16 & 7;   // K frag-read chunk swizzle (8 chunks/row)

    for (int kt = 0; kt < SS / 128; ++kt) {
        const int kb = kt * 128;
        __syncthreads();   // frag reads of previous tile complete
        // K: 1024 chunks (128 rows x 8); LDS chunk c holds global chunk
        // (c&7)^(row&7) of row c>>3.
        #pragma unroll
        for (int j = 0; j < 4; ++j) {
            const int cb = wave * 64 + j * 256;
            const int c  = cb + lane;
            const int row = c >> 3, cc = (c & 7) ^ (row & 7);
            gll16(&K[base + (size_t)(kb + row) * EE + cc * 8], &Ks[cb * 8]);
        }
        // V: 1024 chunks (64 rows x 16); LDS chunk c holds global k-chunk
        // (c&15)^(row&15) of d-row c>>4.
        #pragma unroll
        for (int j = 0; j < 4; ++j) {
            const int cb = wave * 64 + j * 256;
            const int c  = cb + lane;
            const int row = c >> 4, cc = (c & 15) ^ (row & 15);
            gll16(&Vt[base_vt + (size_t)row * SS + kb + cc * 8], &Vs[cb * 8]);
        }
        __syncthreads();   // vmcnt(0) drain completes the DMA

        // S^T = mfma(kf, qf): lane(quad,r16) gets st[tn][r] =
        //   S[q = r16][k = tn*16 + quad*4 + r],  tn = 0..7.
        f32x4 st[8];
        #pragma unroll
        for (int tn = 0; tn < 8; ++tn) st[tn] = zero;
        #pragma unroll
        for (int tn = 0; tn < 8; ++tn) {
            bf16x8 kf0 = *reinterpret_cast<const bf16x8*>(&Ks[((tn * 16 + r16) * 8 + (quad ^ swzk)) * 8]);
            bf16x8 kf1 = *reinterpret_cast<const bf16x8*>(&Ks[((tn * 16 + r16) * 8 + ((quad + 4) ^ swzk)) * 8]);
            st[tn] = __builtin_amdgcn_mfma_f32_16x16x32_bf16(kf0, qf0, st[tn], 0, 0, 0);
            st[tn] = __builtin_amdgcn_mfma_f32_16x16x32_bf16(kf1, qf1, st[tn], 0, 0, 0);
        }

        // m=0 softmax; pack 4 consecutive-k p's -> one b64 LDS write per tn.
        #pragma unroll
        for (int tn = 0; tn < 8; ++tn) {
            const float p0 = exp2f(st[tn][0] * eqs);
            const float p1 = exp2f(st[tn][1] * eqs);
            const float p2 = exp2f(st[tn][2] * eqs);
            const float p3 = exp2f(st[tn][3] * eqs);
            l_lane += (p0 + p1) + (p2 + p3);
            uint2 d;
            d.x = pk2(p0, p1);
            d.y = pk2(p2, p3);
            *reinterpret_cast<uint2*>(&pw[r16 * PROW + tn * 16 + quad * 4]) = d;
        }
        // Per-wave P buffer: in-wave lgkm ordering suffices, no barrier.

        // PV over 4 k-windows of 32: a = P[m=q=r16][k = g*32 + quad*8 + j],
        // b = Vs[n=d][same k] (global k-chunk 4g+quad, LDS chunk ^r16).
        #pragma unroll
        for (int g = 0; g < 4; ++g) {
            bf16x8 pf = *reinterpret_cast<bf16x8*>(&pw[r16 * PROW + g * 32 + quad * 8]);
            #pragma unroll
            for (int dt = 0; dt < 4; ++dt) {
                bf16x8 vf = *reinterpret_cast<const bf16x8*>(
                    &Vs[((dt * 16 + r16) * 16 + ((4 * g + quad) ^ r16)) * 8]);
                o_acc[dt] = __builtin_amdgcn_mfma_f32_16x16x32_bf16(pf, vf, o_acc[dt], 0, 0, 0);
            }
        }
    }

    // l: per-lane total for q = r16; sum the 4 quads.
    float l = l_lane;
    l += __shfl_xor(l, 16, 64);
    l += __shfl_xor(l, 32, 64);

    // Epilogue: O rows q = quad*4+r; l for that q lives in lane (quad*4+r).
    #pragma unroll
    for (int r = 0; r < 4; ++r) {
        const float il = 1.0f / __shfl(l, quad * 4 + r, 64);
        const int q = q0 + wave * 16 + quad * 4 + r;
        #pragma unroll
        for (int dt = 0; dt < 4; ++dt)
            O[base + (size_t)q * EE + dt * 16 + r16] = f2bf(o_acc[dt][r] * il);
    }
}

extern "C" void kernel_launch(void* const* d_in, const int* in_sizes, int n_in,
                              void* d_out, int out_size, void* d_ws, size_t ws_size,
                              hipStream_t stream) {
    const float* x   = (const float*)d_in[0];
    const float* ent = (const float*)d_in[1];
    const float* Wq  = (const float*)d_in[2];
    const float* bq  = (const float*)d_in[3];
    const float* Wk  = (const float*)d_in[4];
    const float* bk  = (const float*)d_in[5];
    const float* Wv  = (const float*)d_in[6];
    const float* bv  = (const float*)d_in[7];
    const float* Wo  = (const float*)d_in[8];
    const float* bo  = (const float*)d_in[9];
    float* out = (float*)d_out;

    const size_t n_x = (size_t)BB * SS * EE;   // 4 Mi elements
    const size_t n_w = (size_t)EE * EE;

    unsigned short* xb  = (unsigned short*)d_ws;
    unsigned short* wqb = xb + n_x;
    unsigned short* wkb = wqb + n_w;
    unsigned short* wvb = wkb + n_w;
    unsigned short* wob = wvb + n_w;
    unsigned short* Qb  = wob + n_w;
    unsigned short* Kb  = Qb + n_x;
    unsigned short* Vtb = Kb + n_x;   // [b][h][d][s]
    unsigned short* AOb = Vtb + n_x;

    const int M = BB * SS;  // 8192

    dim3 gc(4096, 5, 1);
    cast_all<<<gc, 256, 0, stream>>>(x, Wq, Wk, Wv, Wo, xb, wqb, wkb, wvb, wob);

    // Fused QKV projection.
    dim3 gq(M / 128, EE / 128, 3);
    gemm_mfma_nt<unsigned short, true, 128><<<gq, 256, 0, stream>>>(
        xb, wqb, bq, Qb, wkb, bk, Kb, wvb, bv, Vtb, M, EE, EE);

    dim3 ga(SS / 64, HH, BB);
    attn_mfma<<<ga, 256, 0, stream>>>(Qb, Kb, Vtb, ent, AOb);

    // Out-proj: 64x128 tiles -> 512 blocks (2/CU).
    dim3 go(M / 64, EE / 128, 1);
    gemm_mfma_nt<float, false, 64><<<go, 256, 0, stream>>>(
        AOb, wob, bo, out, wob, bo, out, wob, bo, out, M, EE, EE);
}

// Round 11
// 202.790 us; speedup vs baseline: 1.1339x; 1.0439x over previous
//
#include <hip/hip_runtime.h>
#include <hip/hip_bf16.h>

#define BB 4
#define SS 2048
#define EE 512
#define HH 8
#define DD 64

typedef __attribute__((ext_vector_type(8))) short bf16x8;   // 8 bf16 = 4 VGPRs
typedef __attribute__((ext_vector_type(4))) float f32x4;

// NOTE: __float2bfloat16 folds to a single v_cvt on gfx950 — the r10
// integer-trick replacement was 3 VALU ops and regressed the rest-of-pipe
// by ~11 us. Keep the intrinsic.
__device__ __forceinline__ unsigned short f2bf(float f) {
    __hip_bfloat16 h = __float2bfloat16(f);   // round-to-nearest
    return *reinterpret_cast<unsigned short*>(&h);
}
__device__ __forceinline__ unsigned int pk2(float lo, float hi) {
    return ((unsigned int)f2bf(hi) << 16) | (unsigned int)f2bf(lo);
}

// Async global->LDS DMA, 16 B per lane. LDS dst = wave-uniform base + lane*16
// (m104/m108). Drained by the vmcnt(0) inside __syncthreads().
__device__ __forceinline__ void gll16(const unsigned short* g, unsigned short* l) {
    __builtin_amdgcn_global_load_lds(
        (const __attribute__((address_space(1))) unsigned int*)g,
        (__attribute__((address_space(3))) unsigned int*)l,
        16, 0, 0);
}

// ---------------------------------------------------------------------------
// fp32 -> bf16 cast, 5 tensors in one launch (blockIdx.y selects).
// ---------------------------------------------------------------------------
__global__ __launch_bounds__(256)
void cast_all(const float* __restrict__ x,
              const float* __restrict__ wq, const float* __restrict__ wk,
              const float* __restrict__ wv, const float* __restrict__ wo,
              unsigned short* __restrict__ xb,
              unsigned short* __restrict__ wqb, unsigned short* __restrict__ wkb,
              unsigned short* __restrict__ wvb, unsigned short* __restrict__ wob)
{
    const int t = blockIdx.y;
    const float* src; unsigned short* dst; int n4;
    switch (t) {
        case 0: src = x;  dst = xb;  n4 = (BB*SS*EE)/4; break;
        case 1: src = wq; dst = wqb; n4 = (EE*EE)/4; break;
        case 2: src = wk; dst = wkb; n4 = (EE*EE)/4; break;
        case 3: src = wv; dst = wvb; n4 = (EE*EE)/4; break;
        default: src = wo; dst = wob; n4 = (EE*EE)/4; break;
    }
    const int i = blockIdx.x * 256 + threadIdx.x;
    if (i >= n4) return;
    const float4 v = reinterpret_cast<const float4*>(src)[i];
    ushort4 o;
    o.x = f2bf(v.x); o.y = f2bf(v.y); o.z = f2bf(v.z); o.w = f2bf(v.w);
    reinterpret_cast<ushort4*>(dst)[i] = o;
}

// ---------------------------------------------------------------------------
// MFMA GEMM, BK=64: C = A(bf16) @ W(bf16)^T + bias.
// TM x 128 tile, 4 waves, 16x16x32 bf16 MFMA. Halved barrier count vs BK=32
// (8 iters for K=512, 32 MFMA/wave between drains). LDS 32 KB (TM=128) ->
// still 5 blocks/CU capacity. Staging/read swizzle = the attn r8 pattern
// (8-chunk rows, cc=(c&7)^(row&7); frag slot (h*4+quad)^(r16&7)) which
// measured 0 bank conflicts. Simple 2-barrier loop (r3/r4/r9: prefetch and
// dbuf variants all regressed).
// TRANSPOSE_V: blockIdx.z==2 writes C transposed per-head as Vt[b][h][d][s].
// ---------------------------------------------------------------------------
template<typename OutT, bool TRANSPOSE_V, int TM>
__global__ __launch_bounds__(256)
void gemm_mfma_nt(const unsigned short* __restrict__ A,
                  const unsigned short* __restrict__ W0, const float* __restrict__ b0, OutT* __restrict__ C0,
                  const unsigned short* __restrict__ W1, const float* __restrict__ b1, OutT* __restrict__ C1,
                  const unsigned short* __restrict__ W2, const float* __restrict__ b2, OutT* __restrict__ C2,
                  int M, int N, int K)
{
    const unsigned short* W = (blockIdx.z == 0) ? W0 : (blockIdx.z == 1) ? W1 : W2;
    const float* bias       = (blockIdx.z == 0) ? b0 : (blockIdx.z == 1) ? b1 : b2;
    OutT* C                 = (blockIdx.z == 0) ? C0 : (blockIdx.z == 1) ? C1 : C2;

    constexpr int MT = TM / 32;               // m-tiles of 16 per wave (4 or 2)
    __shared__ unsigned short As[TM * 64];    // [row][64] chunk-swizzled
    __shared__ unsigned short Bs[128 * 64];

    const int tid  = threadIdx.x;
    const int wave = tid >> 6, lane = tid & 63;
    const int quad = lane >> 4, r16 = lane & 15;
    const int m0 = blockIdx.x * TM, n0 = blockIdx.y * 128;
    const int wm0 = (wave >> 1) * (TM / 2), wn0 = (wave & 1) * 64;

    f32x4 acc[MT][4];
    const f32x4 zero = {0.f, 0.f, 0.f, 0.f};
    #pragma unroll
    for (int i = 0; i < MT; ++i)
        #pragma unroll
        for (int j = 0; j < 4; ++j) acc[i][j] = zero;

    const int swz = r16 & 7;   // fragment-read chunk swizzle (8 chunks/row)

    for (int k0 = 0; k0 < K; k0 += 64) {
        __syncthreads();   // previous iteration's frag reads done
        // A: TM rows x 8 chunks of 16 B.
        #pragma unroll
        for (int j = 0; j < TM / 32; ++j) {
            const int cb = wave * 64 + j * 256;       // wave-uniform chunk base
            const int c  = cb + lane;
            const int row = c >> 3, cc = (c & 7) ^ (row & 7);
            gll16(&A[(size_t)(m0 + row) * K + k0 + cc * 8], &As[cb * 8]);
        }
        // W: 128 rows x 8 chunks.
        #pragma unroll
        for (int j = 0; j < 4; ++j) {
            const int cb = wave * 64 + j * 256;
            const int c  = cb + lane;
            const int row = c >> 3, cc = (c & 7) ^ (row & 7);
            gll16(&W[(size_t)(n0 + row) * K + k0 + cc * 8], &Bs[cb * 8]);
        }
        __syncthreads();   // vmcnt(0) drain completes the DMA

        #pragma unroll
        for (int h = 0; h < 2; ++h) {      // two 32-wide k halves
            bf16x8 af[MT], bfr[4];
            #pragma unroll
            for (int t = 0; t < MT; ++t)
                af[t]  = *reinterpret_cast<bf16x8*>(
                    &As[((wm0 + t * 16 + r16) * 8 + ((h * 4 + quad) ^ swz)) * 8]);
            #pragma unroll
            for (int t = 0; t < 4; ++t)
                bfr[t] = *reinterpret_cast<bf16x8*>(
                    &Bs[((wn0 + t * 16 + r16) * 8 + ((h * 4 + quad) ^ swz)) * 8]);
            #pragma unroll
            for (int mt = 0; mt < MT; ++mt)
                #pragma unroll
                for (int nt = 0; nt < 4; ++nt)
                    acc[mt][nt] = __builtin_amdgcn_mfma_f32_16x16x32_bf16(
                        af[mt], bfr[nt], acc[mt][nt], 0, 0, 0);
        }
    }

    // Epilogue. C/D layout: col = lane&15, row = quad*4 + reg (m89-verified).
    if (TRANSPOSE_V && blockIdx.z == 2) {
        #pragma unroll
        for (int mt = 0; mt < MT; ++mt) {
            const int m = m0 + wm0 + mt * 16 + quad * 4;   // 4 consecutive rows
            const int bb = m >> 11, s0 = m & (SS - 1);
            #pragma unroll
            for (int nt = 0; nt < 4; ++nt) {
                const int col = n0 + wn0 + nt * 16 + r16;
                const float bv = bias[col];
                ushort4 o;
                o.x = f2bf(acc[mt][nt][0] + bv);
                o.y = f2bf(acc[mt][nt][1] + bv);
                o.z = f2bf(acc[mt][nt][2] + bv);
                o.w = f2bf(acc[mt][nt][3] + bv);
                *reinterpret_cast<ushort4*>(
                    &((unsigned short*)C2)[(size_t)bb * EE * SS + (size_t)col * SS + s0]) = o;
            }
        }
        return;
    }
    #pragma unroll
    for (int mt = 0; mt < MT; ++mt) {
        #pragma unroll
        for (int nt = 0; nt < 4; ++nt) {
            const int col = n0 + wn0 + nt * 16 + r16;
            const float bv = bias[col];
            #pragma unroll
            for (int r = 0; r < 4; ++r) {
                const int row = m0 + wm0 + mt * 16 + quad * 4 + r;
                const float v = acc[mt][nt][r] + bv;
                if constexpr (sizeof(OutT) == 2)
                    C[(size_t)row * N + col] = (OutT)f2bf(v);
                else
                    C[(size_t)row * N + col] = (OutT)v;
            }
        }
    }
}

// ---------------------------------------------------------------------------
// MFMA flash attention — EXACT r8 version (91 us, 0 conflicts).
//  - S^T = mfma(kf, qf); per-lane softmax scale; per-lane l; packed b64 P
//    writes into per-wave Ps (APAD=68).
//  - K/V staged via global_load_lds width 16 into unpadded 64-short rows,
//    XOR chunk swizzle (cc ^ (row&7)): frag b128 reads 2-way max (free).
//  - m=0 softmax (shift-invariant, |s*e| small), exp2 domain.
//  - Simple 2-barrier staging; Tk=64 (r9 dbuf and r10 Tk=128 both lost).
// ---------------------------------------------------------------------------
#define APAD 68

__global__ __launch_bounds__(256)
void attn_mfma(const unsigned short* __restrict__ Q,
               const unsigned short* __restrict__ K,
               const unsigned short* __restrict__ Vt,
               const float* __restrict__ ent,
               unsigned short* __restrict__ O)
{
    __shared__ unsigned short Ks[64 * 64];       // [k][64] chunk-swizzled
    __shared__ unsigned short Vs[64 * 64];       // [d][64] chunk-swizzled
    __shared__ unsigned short Ps[4][16 * APAD];  // per-wave [q16][k64]

    const int tid  = threadIdx.x;
    const int wave = tid >> 6, lane = tid & 63;
    const int quad = lane >> 4, r16 = lane & 15;
    const int q0 = blockIdx.x * 64;
    const int h  = blockIdx.y, b = blockIdx.z;
    const size_t base    = (size_t)b * SS * EE + (size_t)h * DD;   // Q/K/O rows
    const size_t base_vt = ((size_t)b * HH + h) * DD * SS;         // Vt rows

    // Q fragments once, direct from global. B-operand: n = q = r16.
    const int qrow = q0 + wave * 16 + r16;
    bf16x8 qf0 = *reinterpret_cast<const bf16x8*>(&Q[base + (size_t)qrow * EE + quad * 8]);
    bf16x8 qf1 = *reinterpret_cast<const bf16x8*>(&Q[base + (size_t)qrow * EE + 32 + quad * 8]);

    // Per-lane row scale: entangle[q=r16 row] * 1/8 * log2(e).
    const float eqs = ent[q0 + wave * 16 + r16] * (0.125f * 1.44269504f);

    float l_lane = 0.f;
    f32x4 o_acc[4];
    const f32x4 zero = {0.f, 0.f, 0.f, 0.f};
    #pragma unroll
    for (int dt = 0; dt < 4; ++dt) o_acc[dt] = zero;

    unsigned short* pw = &Ps[wave][0];
    const int swz = r16 & 7;   // fragment-read chunk swizzle (8 chunks/row)

    for (int kt = 0; kt < SS / 64; ++kt) {
        const int kb = kt * 64;
        __syncthreads();   // frag reads of previous tile complete
        #pragma unroll
        for (int j = 0; j < 2; ++j) {
            const int cb = wave * 64 + j * 256;
            const int c  = cb + lane;
            const int row = c >> 3, cc = (c & 7) ^ (row & 7);
            gll16(&K[base + (size_t)(kb + row) * EE + cc * 8], &Ks[cb * 8]);
            gll16(&Vt[base_vt + (size_t)row * SS + kb + cc * 8], &Vs[cb * 8]);
        }
        __syncthreads();   // vmcnt(0) drain completes the DMA

        // S^T = mfma(kf, qf): lane(quad,r16) gets st[tn][r] =
        //   S[q = r16][k = tn*16 + quad*4 + r].
        f32x4 st[4];
        #pragma unroll
        for (int tn = 0; tn < 4; ++tn) st[tn] = zero;
        #pragma unroll
        for (int tn = 0; tn < 4; ++tn) {
            bf16x8 kf0 = *reinterpret_cast<const bf16x8*>(&Ks[((tn * 16 + r16) * 8 + (quad ^ swz)) * 8]);
            bf16x8 kf1 = *reinterpret_cast<const bf16x8*>(&Ks[((tn * 16 + r16) * 8 + ((quad + 4) ^ swz)) * 8]);
            st[tn] = __builtin_amdgcn_mfma_f32_16x16x32_bf16(kf0, qf0, st[tn], 0, 0, 0);
            st[tn] = __builtin_amdgcn_mfma_f32_16x16x32_bf16(kf1, qf1, st[tn], 0, 0, 0);
        }

        // V fragments (independent of softmax -> overlaps it).
        bf16x8 vf0[4], vf1[4];
        #pragma unroll
        for (int dt = 0; dt < 4; ++dt) {
            vf0[dt] = *reinterpret_cast<const bf16x8*>(&Vs[((dt * 16 + r16) * 8 + (quad ^ swz)) * 8]);
            vf1[dt] = *reinterpret_cast<const bf16x8*>(&Vs[((dt * 16 + r16) * 8 + ((quad + 4) ^ swz)) * 8]);
        }

        // m=0 softmax; pack 4 consecutive-k p's -> one b64 LDS write per tn.
        #pragma unroll
        for (int tn = 0; tn < 4; ++tn) {
            const float p0 = exp2f(st[tn][0] * eqs);
            const float p1 = exp2f(st[tn][1] * eqs);
            const float p2 = exp2f(st[tn][2] * eqs);
            const float p3 = exp2f(st[tn][3] * eqs);
            l_lane += (p0 + p1) + (p2 + p3);
            uint2 d;
            d.x = pk2(p0, p1);
            d.y = pk2(p2, p3);
            *reinterpret_cast<uint2*>(&pw[r16 * APAD + tn * 16 + quad * 4]) = d;
        }
        // Per-wave P buffer: in-wave lgkm ordering suffices, no barrier.

        // PV: a = P[m=q=r16][k = quad*8+j], b = Vs[n=d=r16][k].
        bf16x8 pf0 = *reinterpret_cast<bf16x8*>(&pw[r16 * APAD + quad * 8]);
        bf16x8 pf1 = *reinterpret_cast<bf16x8*>(&pw[r16 * APAD + 32 + quad * 8]);
        #pragma unroll
        for (int dt = 0; dt < 4; ++dt) {
            o_acc[dt] = __builtin_amdgcn_mfma_f32_16x16x32_bf16(pf0, vf0[dt], o_acc[dt], 0, 0, 0);
            o_acc[dt] = __builtin_amdgcn_mfma_f32_16x16x32_bf16(pf1, vf1[dt], o_acc[dt], 0, 0, 0);
        }
    }

    // l: per-lane total for q = r16; sum the 4 quads.
    float l = l_lane;
    l += __shfl_xor(l, 16, 64);
    l += __shfl_xor(l, 32, 64);

    // Epilogue: O rows q = quad*4+r; l for that q lives in lane (quad*4+r).
    #pragma unroll
    for (int r = 0; r < 4; ++r) {
        const float il = 1.0f / __shfl(l, quad * 4 + r, 64);
        const int q = q0 + wave * 16 + quad * 4 + r;
        #pragma unroll
        for (int dt = 0; dt < 4; ++dt)
            O[base + (size_t)q * EE + dt * 16 + r16] = f2bf(o_acc[dt][r] * il);
    }
}

extern "C" void kernel_launch(void* const* d_in, const int* in_sizes, int n_in,
                              void* d_out, int out_size, void* d_ws, size_t ws_size,
                              hipStream_t stream) {
    const float* x   = (const float*)d_in[0];
    const float* ent = (const float*)d_in[1];
    const float* Wq  = (const float*)d_in[2];
    const float* bq  = (const float*)d_in[3];
    const float* Wk  = (const float*)d_in[4];
    const float* bk  = (const float*)d_in[5];
    const float* Wv  = (const float*)d_in[6];
    const float* bv  = (const float*)d_in[7];
    const float* Wo  = (const float*)d_in[8];
    const float* bo  = (const float*)d_in[9];
    float* out = (float*)d_out;

    const size_t n_x = (size_t)BB * SS * EE;   // 4 Mi elements
    const size_t n_w = (size_t)EE * EE;

    unsigned short* xb  = (unsigned short*)d_ws;
    unsigned short* wqb = xb + n_x;
    unsigned short* wkb = wqb + n_w;
    unsigned short* wvb = wkb + n_w;
    unsigned short* wob = wvb + n_w;
    unsigned short* Qb  = wob + n_w;
    unsigned short* Kb  = Qb + n_x;
    unsigned short* Vtb = Kb + n_x;   // [b][h][d][s]
    unsigned short* AOb = Vtb + n_x;

    const int M = BB * SS;  // 8192

    dim3 gc(4096, 5, 1);
    cast_all<<<gc, 256, 0, stream>>>(x, Wq, Wk, Wv, Wo, xb, wqb, wkb, wvb, wob);

    // Fused QKV projection.
    dim3 gq(M / 128, EE / 128, 3);
    gemm_mfma_nt<unsigned short, true, 128><<<gq, 256, 0, stream>>>(
        xb, wqb, bq, Qb, wkb, bk, Kb, wvb, bv, Vtb, M, EE, EE);

    dim3 ga(SS / 64, HH, BB);
    attn_mfma<<<ga, 256, 0, stream>>>(Qb, Kb, Vtb, ent, AOb);

    // Out-proj: 64x128 tiles -> 512 blocks (2/CU).
    dim3 go(M / 64, EE / 128, 1);
    gemm_mfma_nt<float, false, 64><<<go, 256, 0, stream>>>(
        AOb, wob, bo, out, wob, bo, out, wob, bo, out, M, EE, EE);
}